// Round 4
// baseline (227.319 us; speedup 1.0000x reference)
//
#include <hip/hip_runtime.h>
#include <hip/hip_bf16.h>
#include <math.h>
#include <stddef.h>

// Problem shape: z [4,64,16,32,32] fp32, embedding [1024,64] fp32
#define CH     64
#define DHWC   16384
#define NTOK   65536
#define KCODES 1024
#define OUT_ELEMS 4194304

typedef _Float16 f16;
typedef f16  f16x8  __attribute__((ext_vector_type(8)));
typedef float fltx4 __attribute__((ext_vector_type(4)));

struct Ws {
  // ---- zeroed header (memset range = offsetof(Ws, e_norm)) ----
  double sum_z2, sum_e2, loss_sum;
  int    ticket, pad0;
  float  sum_z[CH];               // native f32 atomics from gemm blocks
  double sum_e[CH];
  int    counts[KCODES];
  // ---- filled by eprep ----
  float  e_norm[KCODES];
  float  accI[KCODES + 48];       // -e_norm/2; +48 pad for depth-2 prefetch
  // codebook pre-swizzled into MFMA B-fragment order (verified):
  // +2 pad rows for depth-2 prefetch overrun (values loaded, never used)
  f16    e_frag[(64 + 2) * 2 * 64 * 8];
  // ---- final winner per token (gemm -> writer) ----
  unsigned short wk[NTOK];
};

// ---- eprep: e_norm (exact chain) + channel sums + sum_e2 + fragments ----
__global__ void vq_eprep(const float* __restrict__ emb, Ws* __restrict__ ws) {
  __shared__ float tile[64][68];
  __shared__ float red[256];
  const int tid = threadIdx.x;
  const int r = tid >> 2;                 // code row within block (0..63)
  const int q = tid & 3;                  // quarter of the 64-channel row
  const int k = blockIdx.x * 64 + r;
  const float4* src = (const float4*)(emb + (size_t)k * CH + q * 16);
  float4 a = src[0], b = src[1], c = src[2], d = src[3];
  float4* dst = (float4*)(&tile[r][q * 16]);
  dst[0] = a; dst[1] = b; dst[2] = c; dst[3] = d;
  float s2 = 0.f;
  s2 = fmaf(a.x,a.x,s2); s2 = fmaf(a.y,a.y,s2); s2 = fmaf(a.z,a.z,s2); s2 = fmaf(a.w,a.w,s2);
  s2 = fmaf(b.x,b.x,s2); s2 = fmaf(b.y,b.y,s2); s2 = fmaf(b.z,b.z,s2); s2 = fmaf(b.w,b.w,s2);
  s2 = fmaf(c.x,c.x,s2); s2 = fmaf(c.y,c.y,s2); s2 = fmaf(c.z,c.z,s2); s2 = fmaf(c.w,c.w,s2);
  s2 = fmaf(d.x,d.x,s2); s2 = fmaf(d.y,d.y,s2); s2 = fmaf(d.z,d.z,s2); s2 = fmaf(d.w,d.w,s2);
  // verified-exact row norm (absmax 0.0)
  float t1 = s2 + __shfl_xor(s2, 1);
  float t2 = t1 + __shfl_xor(t1, 2);
  if (q == 0) { ws->e_norm[k] = t2; ws->accI[k] = -0.5f * t2; }
  // pre-swizzled B-fragment write (verified)
  {
    float vals[16] = {a.x,a.y,a.z,a.w, b.x,b.y,b.z,b.w,
                      c.x,c.y,c.z,c.w, d.x,d.y,d.z,d.w};
    const int ct  = blockIdx.x * 4 + (r >> 4);
    const int nn  = r & 15;
    const int b01 = q >> 1;
    const int qd0 = (q & 1) * 2;
    f16 h8a[8], h8b[8];
    #pragma unroll
    for (int u = 0; u < 8; ++u) { h8a[u] = (f16)vals[u]; h8b[u] = (f16)vals[8 + u]; }
    f16x8* fr = (f16x8*)ws->e_frag;
    fr[(ct * 2 + b01) * 64 + (qd0 + 0) * 16 + nn] = *(f16x8*)h8a;
    fr[(ct * 2 + b01) * 64 + (qd0 + 1) * 16 + nn] = *(f16x8*)h8b;
  }
  red[tid] = s2;
  __syncthreads();
  for (int off = 128; off > 0; off >>= 1) {
    if (tid < off) red[tid] += red[tid + off];
    __syncthreads();
  }
  if (tid == 0) atomicAdd(&ws->sum_e2, (double)red[0]);
  if (tid < CH) {
    float cs = 0.f;
    #pragma unroll 8
    for (int rr = 0; rr < 64; ++rr) cs += tile[rr][tid];
    atomicAdd(&ws->sum_e[tid], (double)cs);
  }
}

// ---- phase 1+2: MFMA candidates + funnel + exact recheck + final winner -
// R4: grid 2048 blocks x 32 tokens; 4 waves each take a K-QUARTER of the
// same 32 tokens (loop shape = verified R2/R3: 2 B-loads + accI -> 4 MFMA
// -> packed-key top-2/class). Small LDS (23.5KB) + small regs -> ~5
// blocks/CU (20 waves) for latency hiding. Winner finalized in-block.
__global__ __launch_bounds__(256, 5)
void vq_gemm(const float* __restrict__ z, const float* __restrict__ emb,
             Ws* __restrict__ ws) {
  // LDS: [0,4608) zh f16[32][72]; [4608,21504) cand f32[32][132];
  //      [21504,23552) shs f32[512]
  __shared__ char smem[23552];
  f16*   zh   = (f16*)smem;
  float* cand = (float*)(smem + 4608);
  float* shs  = (float*)(smem + 21504);

  const int tid = threadIdx.x;
  const int n0  = blockIdx.x * 32;         // global token base
  const int b   = n0 >> 14;
  const int s0  = n0 & 16383;
  const float* zbase = z + (size_t)b * (CH * DHWC) + s0;

  // stage z -> f16 [token][c] (stride 72); all blocks do channel sums
  {
    const int c = tid >> 2;            // 0..63
    const int q = tid & 3;             // token quarter (8 tokens)
    const float4* src = (const float4*)(zbase + (size_t)c * DHWC) + q * 2;
    float ss = 0.f, ss2 = 0.f;
    #pragma unroll
    for (int i = 0; i < 2; ++i) {
      float4 v = src[i];
      const int t0 = q * 8 + i * 4;
      zh[(t0 + 0) * 72 + c] = (f16)v.x;
      zh[(t0 + 1) * 72 + c] = (f16)v.y;
      zh[(t0 + 2) * 72 + c] = (f16)v.z;
      zh[(t0 + 3) * 72 + c] = (f16)v.w;
      ss += v.x + v.y + v.z + v.w;
      ss2 = fmaf(v.x, v.x, ss2); ss2 = fmaf(v.y, v.y, ss2);
      ss2 = fmaf(v.z, v.z, ss2); ss2 = fmaf(v.w, v.w, ss2);
    }
    shs[tid] = ss; shs[256 + tid] = ss2;
  }
  __syncthreads();
  if (tid < 64) {
    float cs = shs[4*tid] + shs[4*tid+1] + shs[4*tid+2] + shs[4*tid+3];
    atomicAdd(&ws->sum_z[tid], cs);
    float cs2 = shs[256+4*tid] + shs[256+4*tid+1] + shs[256+4*tid+2] + shs[256+4*tid+3];
    #pragma unroll
    for (int off = 32; off > 0; off >>= 1) cs2 += __shfl_down(cs2, off);
    if (tid == 0) atomicAdd(&ws->sum_z2, (double)cs2);
  }

  const int lane = tid & 63;
  const int w    = tid >> 6;           // wave -> K-quarter w
  const int nn   = lane & 15;          // MFMA column (code class)
  const int quad = lane >> 4;

  // A fragments (verified layout): A[m=lane&15][k=quad*8+j], 2 M-tiles
  f16x8 Ah[2][2];
  #pragma unroll
  for (int mt = 0; mt < 2; ++mt) {
    const int row = mt * 16 + nn;
    #pragma unroll
    for (int ks = 0; ks < 2; ++ks)
      Ah[mt][ks] = *(const f16x8*)(&zh[row * 72 + ks * 32 + quad * 8]);
  }

  // packed-key top-2 per (token-slot, class):
  // key = (score bits & ~1023) | (1023 - k): distinct keys, max = best,
  // k decodable from low 10 bits; exact distances restored by recheck.
  float m1[8], m2[8];
  #pragma unroll
  for (int u = 0; u < 8; ++u) { m1[u] = -3.4e38f; m2[u] = -3.4e38f; }

  const f16x8* __restrict__ fr  = ((const f16x8*)ws->e_frag) + lane;
  const float* __restrict__ aIp = ws->accI;

  int ct = w * 16;                     // this wave's quarter: 16 iterations
  f16x8 B0a = fr[(ct * 2 + 0) * 64];
  f16x8 B1a = fr[(ct * 2 + 1) * 64];
  f16x8 B0b = fr[(ct * 2 + 2) * 64];
  f16x8 B1b = fr[(ct * 2 + 3) * 64];
  float aia = aIp[ct * 16 + nn];
  float aib = aIp[ct * 16 + 16 + nn];
  unsigned orb = (unsigned)(1023 - ct * 16 - nn);
  #pragma unroll 2
  for (int it = 0; it < 16; ++it) {
    const int pct = ct + 2;            // depth-2 prefetch (pads/next quarter)
    f16x8 nB0 = fr[(pct * 2 + 0) * 64];
    f16x8 nB1 = fr[(pct * 2 + 1) * 64];
    const float nai = aIp[pct * 16 + nn];
    fltx4 acc0 = {aia, aia, aia, aia};
    acc0 = __builtin_amdgcn_mfma_f32_16x16x32_f16(Ah[0][0], B0a, acc0, 0, 0, 0);
    acc0 = __builtin_amdgcn_mfma_f32_16x16x32_f16(Ah[0][1], B1a, acc0, 0, 0, 0);
    fltx4 acc1 = {aia, aia, aia, aia};
    acc1 = __builtin_amdgcn_mfma_f32_16x16x32_f16(Ah[1][0], B0a, acc1, 0, 0, 0);
    acc1 = __builtin_amdgcn_mfma_f32_16x16x32_f16(Ah[1][1], B1a, acc1, 0, 0, 0);
    #pragma unroll
    for (int r = 0; r < 4; ++r) {
      unsigned t0 = (__float_as_uint(acc0[r]) & 0xFFFFFC00u) | orb;
      float k0 = __uint_as_float(t0);
      m2[r] = fmaxf(m2[r], fminf(m1[r], k0));
      m1[r] = fmaxf(m1[r], k0);
      unsigned t1 = (__float_as_uint(acc1[r]) & 0xFFFFFC00u) | orb;
      float k1 = __uint_as_float(t1);
      m2[4+r] = fmaxf(m2[4+r], fminf(m1[4+r], k1));
      m1[4+r] = fmaxf(m1[4+r], k1);
    }
    orb -= 16;
    ++ct;
    B0a = B0b; B1a = B1b; aia = aib;
    B0b = nB0; B1b = nB1; aib = nai;
  }

  // write per-class top-2 to cand[tok][w*32 + {nn, 16+nn}]
  #pragma unroll
  for (int mt = 0; mt < 2; ++mt)
    #pragma unroll
    for (int r = 0; r < 4; ++r) {
      const int tok = mt * 16 + quad * 4 + r;  // C/D row (verified)
      cand[tok * 132 + w * 32 + nn]      = m1[mt * 4 + r];
      cand[tok * 132 + w * 32 + 16 + nn] = m2[mt * 4 + r];
    }
  __syncthreads();

  // funnel: 128 semis/token -> top-4. 8 threads/token scan 16 each,
  // then 3-step shuffle butterfly merge of sorted top-4 lists.
  const int tok = tid >> 3, seg = tid & 7;
  float bv[4] = {-3.4e38f, -3.4e38f, -3.4e38f, -3.4e38f};
  {
    const float4* cp = (const float4*)(cand + tok * 132 + seg * 16);
    #pragma unroll
    for (int i4 = 0; i4 < 4; ++i4) {
      float4 vv = cp[i4];
      float av[4] = {vv.x, vv.y, vv.z, vv.w};
      #pragma unroll
      for (int e = 0; e < 4; ++e) {
        float a = av[e];
        #pragma unroll
        for (int jj = 0; jj < 4; ++jj) {
          bool ins = a > bv[jj];
          float t = bv[jj]; bv[jj] = ins ? a : bv[jj]; a = ins ? t : a;
        }
      }
    }
  }
  #pragma unroll
  for (int s = 1; s <= 4; s <<= 1) {
    float rv[4];
    #pragma unroll
    for (int jj = 0; jj < 4; ++jj) rv[jj] = __shfl_xor(bv[jj], s);
    #pragma unroll
    for (int e = 0; e < 4; ++e) {
      float a = rv[e];
      #pragma unroll
      for (int jj = 0; jj < 4; ++jj) {
        bool ins = a > bv[jj];
        float t = bv[jj]; bv[jj] = ins ? a : bv[jj]; a = ins ? t : a;
      }
    }
  }

  // exact recheck: 4 lanes/token, one candidate each, full serial chain
  // (bitwise-identical to the verified R3 recheck); (d asc, k asc) winner.
  {
    const int j = tid & 7;
    if (j < 4) {
      const int kc = 1023 - (int)(__float_as_uint(bv[j]) & 1023u);
      const float4* ep = (const float4*)(emb + (size_t)kc * CH);
      const float* zt = zbase + tok;
      float znorm = 0.f, dpr = 0.f;
      #pragma unroll 4
      for (int c4 = 0; c4 < 16; ++c4) {
        float4 ev = ep[c4];
        float v0 = zt[(size_t)(4*c4+0) * DHWC];
        float v1 = zt[(size_t)(4*c4+1) * DHWC];
        float v2 = zt[(size_t)(4*c4+2) * DHWC];
        float v3 = zt[(size_t)(4*c4+3) * DHWC];
        znorm = fmaf(v0, v0, znorm); znorm = fmaf(v1, v1, znorm);
        znorm = fmaf(v2, v2, znorm); znorm = fmaf(v3, v3, znorm);
        dpr = fmaf(v0, ev.x, dpr); dpr = fmaf(v1, ev.y, dpr);
        dpr = fmaf(v2, ev.z, dpr); dpr = fmaf(v3, ev.w, dpr);
      }
      float dd = fmaf(-2.f, dpr, znorm + ws->e_norm[kc]);
      int   kk = kc;
      float od = __shfl_xor(dd, 1); int ok = __shfl_xor(kk, 1);
      if (od < dd || (od == dd && ok < kk)) { dd = od; kk = ok; }
      od = __shfl_xor(dd, 2); ok = __shfl_xor(kk, 2);
      if (od < dd || (od == dd && ok < kk)) { dd = od; kk = ok; }
      if (j == 0) ws->wk[n0 + tok] = (unsigned short)kk;
    }
  }
}

// ---- phase 3: output + loss + counts + fused final (last block) ---------
// grid 256 x 1024; block = ONE (b,c) plane.
__global__ __launch_bounds__(1024, 4)
void vq_writer(const float* __restrict__ z, const float* __restrict__ emb,
               float* __restrict__ out, Ws* __restrict__ ws) {
  __shared__ float ecol[KCODES];     // column c of emb (4 KB); reused as red
  __shared__ int   hist[KCODES];     // LDS histogram (c==0 blocks only)
  __shared__ float sh[16];
  __shared__ int   lastflag;
  const int p   = blockIdx.x;        // plane: b*64 + c
  const int tid = threadIdx.x;
  const int b = p >> 6, c = p & 63;
  const bool docnt = (c == 0);
  ecol[tid] = emb[(size_t)tid * CH + c];
  if (docnt) hist[tid] = 0;
  __syncthreads();

  const size_t base = (size_t)p * DHWC;
  const float4* zp = (const float4*)(z + base);
  float4* op = (float4*)(out + base);
  const unsigned short* wkb = ws->wk + b * 16384;
  float lp = 0.f;
  #pragma unroll
  for (int i = tid; i < 4096; i += 1024) {         // 4 iterations
    float4 v  = zp[i];
    ushort4 kw = *(const ushort4*)(wkb + 4 * i);
    float q0 = ecol[kw.x], q1 = ecol[kw.y], q2 = ecol[kw.z], q3 = ecol[kw.w];
    float e0 = q0 - v.x, e1 = q1 - v.y, e2 = q2 - v.z, e3 = q3 - v.w;
    float4 o; o.x = v.x + e0; o.y = v.y + e1; o.z = v.z + e2; o.w = v.w + e3;
    op[i] = o;
    lp = fmaf(e0, e0, lp); lp = fmaf(e1, e1, lp);
    lp = fmaf(e2, e2, lp); lp = fmaf(e3, e3, lp);
    if (docnt) {
      atomicAdd(&hist[kw.x], 1);
      atomicAdd(&hist[kw.y], 1);
      atomicAdd(&hist[kw.z], 1);
      atomicAdd(&hist[kw.w], 1);
    }
  }
  #pragma unroll
  for (int off = 32; off > 0; off >>= 1) lp += __shfl_down(lp, off);
  if ((tid & 63) == 0) sh[tid >> 6] = lp;
  __syncthreads();
  if (docnt) {
    int h2 = hist[tid];
    if (h2) atomicAdd(&ws->counts[tid], h2);
  }
  if (tid == 0) {
    float t = 0.f;
    #pragma unroll
    for (int i = 0; i < 16; ++i) t += sh[i];
    atomicAdd(&ws->loss_sum, (double)t);
  }
  // ---- last-block fused final ----
  __syncthreads();                 // per-wave vmcnt(0): block's atomics at L2
  __threadfence();
  if (tid == 0) lastflag = (atomicAdd(&ws->ticket, 1) == 255);
  __syncthreads();
  if (lastflag) {
    volatile int* vc = ws->counts;
    float pp = (float)vc[tid] * (1.0f / 65536.0f);
    float term = pp * logf(pp + 1e-10f);
    float* red = ecol;             // ecol dead; reuse as reduction buffer
    __syncthreads();
    red[tid] = term;
    __syncthreads();
    for (int off = 512; off > 0; off >>= 1) {
      if (tid < off) red[tid] += red[tid + off];
      __syncthreads();
    }
    if (tid == 0) {
      float perp = expf(-red[0]);
      volatile double* vl = &ws->loss_sum;
      double m = (*vl) / (double)OUT_ELEMS;
      float mf = (float)m;
      float loss = mf + 0.25f * mf;
      double sdot = 0.0;
      #pragma unroll
      for (int cc = 0; cc < CH; ++cc) sdot += (double)ws->sum_z[cc] * ws->sum_e[cc];
      double md = ws->sum_z2 / (double)NTOK + ws->sum_e2 / (double)KCODES
                - 2.0 * sdot / ((double)NTOK * (double)KCODES);
      float* scal = out + OUT_ELEMS;
      scal[0] = loss;
      scal[1] = perp;
      scal[2] = (float)md;
    }
  }
}

extern "C" void kernel_launch(void* const* d_in, const int* in_sizes, int n_in,
                              void* d_out, int out_size, void* d_ws, size_t ws_size,
                              hipStream_t stream) {
  const float* z   = (const float*)d_in[0];
  const float* emb = (const float*)d_in[1];
  float* out = (float*)d_out;
  Ws* ws = (Ws*)d_ws;

  hipMemsetAsync(d_ws, 0, offsetof(Ws, e_norm), stream);
  vq_eprep <<<16,   256,  0, stream>>>(emb, ws);
  vq_gemm  <<<2048, 256,  0, stream>>>(z, emb, ws);
  vq_writer<<<256,  1024, 0, stream>>>(z, emb, out, ws);
}

// Round 5
// 131.945 us; speedup vs baseline: 1.7228x; 1.7228x over previous
//
#include <hip/hip_runtime.h>
#include <hip/hip_bf16.h>
#include <math.h>
#include <stddef.h>

// Problem shape: z [4,64,16,32,32] fp32, embedding [1024,64] fp32
#define CH     64
#define DHWC   16384
#define NTOK   65536
#define KCODES 1024
#define OUT_ELEMS 4194304

typedef _Float16 f16;
typedef f16  f16x8  __attribute__((ext_vector_type(8)));
typedef float fltx4 __attribute__((ext_vector_type(4)));

struct Ws {
  // ---- zeroed header (memset range = offsetof(Ws, e_norm)) ----
  double sum_z2, sum_e2, loss_sum, pad;
  float  sum_z[CH];               // native f32 atomics from gemm h==0 blocks
  double sum_e[CH];
  int    counts[KCODES];
  // ---- filled by eprep ----
  float  e_norm[KCODES];
  float  accI[KCODES + 48];       // -e_norm/2 (+pad, unused now)
  // codebook pre-swizzled into MFMA B-fragment order (verified layout)
  alignas(16) f16 e_frag[(64 + 2) * 2 * 64 * 8];
  // ---- per-half exact winners (gemm -> writer) ----
  float          hd[2 * NTOK];
  unsigned short hk[2 * NTOK];
};

// ---- eprep: e_norm (exact chain) + channel sums + sum_e2 + fragments ----
__global__ void vq_eprep(const float* __restrict__ emb, Ws* __restrict__ ws) {
  __shared__ float tile[64][68];
  __shared__ float red[256];
  const int tid = threadIdx.x;
  const int r = tid >> 2;                 // code row within block (0..63)
  const int q = tid & 3;                  // quarter of the 64-channel row
  const int k = blockIdx.x * 64 + r;
  const float4* src = (const float4*)(emb + (size_t)k * CH + q * 16);
  float4 a = src[0], b = src[1], c = src[2], d = src[3];
  float4* dst = (float4*)(&tile[r][q * 16]);
  dst[0] = a; dst[1] = b; dst[2] = c; dst[3] = d;
  float s2 = 0.f;
  s2 = fmaf(a.x,a.x,s2); s2 = fmaf(a.y,a.y,s2); s2 = fmaf(a.z,a.z,s2); s2 = fmaf(a.w,a.w,s2);
  s2 = fmaf(b.x,b.x,s2); s2 = fmaf(b.y,b.y,s2); s2 = fmaf(b.z,b.z,s2); s2 = fmaf(b.w,b.w,s2);
  s2 = fmaf(c.x,c.x,s2); s2 = fmaf(c.y,c.y,s2); s2 = fmaf(c.z,c.z,s2); s2 = fmaf(c.w,c.w,s2);
  s2 = fmaf(d.x,d.x,s2); s2 = fmaf(d.y,d.y,s2); s2 = fmaf(d.z,d.z,s2); s2 = fmaf(d.w,d.w,s2);
  // verified-exact row norm (absmax 0.0)
  float t1 = s2 + __shfl_xor(s2, 1);
  float t2 = t1 + __shfl_xor(t1, 2);
  if (q == 0) { ws->e_norm[k] = t2; ws->accI[k] = -0.5f * t2; }
  // pre-swizzled B-fragment write (verified)
  {
    float vals[16] = {a.x,a.y,a.z,a.w, b.x,b.y,b.z,b.w,
                      c.x,c.y,c.z,c.w, d.x,d.y,d.z,d.w};
    const int ct  = blockIdx.x * 4 + (r >> 4);
    const int nn  = r & 15;
    const int b01 = q >> 1;
    const int qd0 = (q & 1) * 2;
    f16 h8a[8], h8b[8];
    #pragma unroll
    for (int u = 0; u < 8; ++u) { h8a[u] = (f16)vals[u]; h8b[u] = (f16)vals[8 + u]; }
    f16x8* fr = (f16x8*)ws->e_frag;
    fr[(ct * 2 + b01) * 64 + (qd0 + 0) * 16 + nn] = *(f16x8*)h8a;
    fr[(ct * 2 + b01) * 64 + (qd0 + 1) * 16 + nn] = *(f16x8*)h8b;
  }
  red[tid] = s2;
  __syncthreads();
  for (int off = 128; off > 0; off >>= 1) {
    if (tid < off) red[tid] += red[tid + off];
    __syncthreads();
  }
  if (tid == 0) atomicAdd(&ws->sum_e2, (double)red[0]);
  if (tid < CH) {
    float cs = 0.f;
    #pragma unroll 8
    for (int rr = 0; rr < 64; ++rr) cs += tile[rr][tid];
    atomicAdd(&ws->sum_e[tid], (double)cs);
  }
}

// ---- phase 1+2: B-stationary-in-LDS MFMA + funnel + exact recheck -------
// R5: grid 512 = 256 token-groups x 2 K-halves; 512 threads (8 waves) x
// 256 tokens. The half-codebook B image (64 KB) + accI-half live in LDS:
// the 32-ct loop reads B via ds_read_b128 (no L2 latency on the critical
// path). Selection = verified packed-key top-2-per-class, ct-pair batched.
// Funnel 32 semis -> top-4 -> exact recheck (R3-verified chain) -> hd/hk.
__global__ __launch_bounds__(512, 2)
void vq_gemm(const float* __restrict__ z, const float* __restrict__ emb,
             Ws* __restrict__ ws) {
  // LDS 106 KB:
  // [0,36864)       zh f16[256][72]  -> reused as cand f32[256][36]
  // [36864,102400)  ef: this half's B fragments (64 KB)
  // [102400,104448) accl f32[512]
  // [104448,108544) shs f32[1024]
  __shared__ char smem[108544];
  f16*   zh   = (f16*)smem;
  float* cand = (float*)smem;
  f16x8* efr  = (f16x8*)(smem + 36864);
  float* accl = (float*)(smem + 102400);
  float* shs  = (float*)(smem + 104448);

  const int tid = threadIdx.x;
  const int h   = blockIdx.x & 1;          // K-half
  const int tg  = blockIdx.x >> 1;         // token group (256 tokens)
  const int n0  = tg * 256;
  const int b   = n0 >> 14;
  const int s0  = n0 & 16383;
  const float* zbase = z + (size_t)b * (CH * DHWC) + s0;

  // stage B-half + accI-half into LDS (coalesced 16B/lane, 8 rounds)
  {
    const f16x8* gsrc = ((const f16x8*)ws->e_frag) + h * 4096;
    #pragma unroll
    for (int r = 0; r < 8; ++r)
      efr[r * 512 + tid] = gsrc[r * 512 + tid];
    accl[tid] = ws->accI[h * 512 + tid];
  }
  // stage z -> f16 [token][c] (stride 72); h==0 blocks also do channel sums
  {
    const int c = tid >> 3;            // 0..63
    const int q = tid & 7;             // token octant (32 tokens)
    const float4* src = (const float4*)(zbase + (size_t)c * DHWC) + q * 8;
    float ss = 0.f, ss2 = 0.f;
    #pragma unroll
    for (int i = 0; i < 8; ++i) {
      float4 v = src[i];
      const int t0 = q * 32 + i * 4;
      zh[(t0 + 0) * 72 + c] = (f16)v.x;
      zh[(t0 + 1) * 72 + c] = (f16)v.y;
      zh[(t0 + 2) * 72 + c] = (f16)v.z;
      zh[(t0 + 3) * 72 + c] = (f16)v.w;
      ss += v.x + v.y + v.z + v.w;
      ss2 = fmaf(v.x, v.x, ss2); ss2 = fmaf(v.y, v.y, ss2);
      ss2 = fmaf(v.z, v.z, ss2); ss2 = fmaf(v.w, v.w, ss2);
    }
    shs[tid] = ss; shs[512 + tid] = ss2;
  }
  __syncthreads();
  if (h == 0 && tid < 64) {
    float cs = 0.f, cs2 = 0.f;
    #pragma unroll
    for (int j = 0; j < 8; ++j) {
      cs  += shs[tid * 8 + j];
      cs2 += shs[512 + tid * 8 + j];
    }
    atomicAdd(&ws->sum_z[tid], cs);
    #pragma unroll
    for (int off = 32; off > 0; off >>= 1) cs2 += __shfl_down(cs2, off);
    if (tid == 0) atomicAdd(&ws->sum_z2, (double)cs2);
  }

  const int lane = tid & 63;
  const int w    = tid >> 6;           // wave: tokens [w*32, w*32+32)
  const int nn   = lane & 15;          // MFMA column (code class)
  const int quad = lane >> 4;

  // A fragments (verified layout): A[m=lane&15][k=quad*8+j]
  f16x8 Ah[2][2];
  #pragma unroll
  for (int mt = 0; mt < 2; ++mt) {
    const int row = w * 32 + mt * 16 + nn;
    #pragma unroll
    for (int ks = 0; ks < 2; ++ks)
      Ah[mt][ks] = *(const f16x8*)(&zh[row * 72 + ks * 32 + quad * 8]);
  }

  // packed-key top-2 per (token-slot, class):
  // key = (score bits & ~1023) | (1023 - k): distinct keys, max = best,
  // k decodable from low 10 bits; exact distances restored by recheck.
  float m1[8], m2[8];
  #pragma unroll
  for (int u = 0; u < 8; ++u) { m1[u] = -3.4e38f; m2[u] = -3.4e38f; }

  const f16x8* Bp = efr + lane;
  unsigned orb = (unsigned)(1023 - h * 512 - nn);
  #pragma unroll 4
  for (int itp = 0; itp < 16; ++itp) {     // ct-pair per iteration
    const int c0 = itp * 2;
    f16x8 B0a = Bp[(c0 * 2 + 0) * 64];
    f16x8 B1a = Bp[(c0 * 2 + 1) * 64];
    f16x8 B0b = Bp[(c0 * 2 + 2) * 64];
    f16x8 B1b = Bp[(c0 * 2 + 3) * 64];
    const float aia = accl[c0 * 16 + nn];
    const float aib = accl[c0 * 16 + 16 + nn];
    fltx4 acc0a = {aia, aia, aia, aia};
    acc0a = __builtin_amdgcn_mfma_f32_16x16x32_f16(Ah[0][0], B0a, acc0a, 0, 0, 0);
    acc0a = __builtin_amdgcn_mfma_f32_16x16x32_f16(Ah[0][1], B1a, acc0a, 0, 0, 0);
    fltx4 acc1a = {aia, aia, aia, aia};
    acc1a = __builtin_amdgcn_mfma_f32_16x16x32_f16(Ah[1][0], B0a, acc1a, 0, 0, 0);
    acc1a = __builtin_amdgcn_mfma_f32_16x16x32_f16(Ah[1][1], B1a, acc1a, 0, 0, 0);
    fltx4 acc0b = {aib, aib, aib, aib};
    acc0b = __builtin_amdgcn_mfma_f32_16x16x32_f16(Ah[0][0], B0b, acc0b, 0, 0, 0);
    acc0b = __builtin_amdgcn_mfma_f32_16x16x32_f16(Ah[0][1], B1b, acc0b, 0, 0, 0);
    fltx4 acc1b = {aib, aib, aib, aib};
    acc1b = __builtin_amdgcn_mfma_f32_16x16x32_f16(Ah[1][0], B0b, acc1b, 0, 0, 0);
    acc1b = __builtin_amdgcn_mfma_f32_16x16x32_f16(Ah[1][1], B1b, acc1b, 0, 0, 0);
    const unsigned oA = orb, oB = orb - 16;
    #pragma unroll
    for (int r = 0; r < 4; ++r) {
      // slot r (M-tile 0): pairwise top-2 update with keys from ct, ct+1
      float ka = __uint_as_float((__float_as_uint(acc0a[r]) & 0xFFFFFC00u) | oA);
      float kb = __uint_as_float((__float_as_uint(acc0b[r]) & 0xFFFFFC00u) | oB);
      float hi = fmaxf(ka, kb), lo = fminf(ka, kb);
      m2[r] = fmaxf(fmaxf(fminf(m1[r], hi), lo), m2[r]);
      m1[r] = fmaxf(m1[r], hi);
      // slot 4+r (M-tile 1)
      float kc = __uint_as_float((__float_as_uint(acc1a[r]) & 0xFFFFFC00u) | oA);
      float kd = __uint_as_float((__float_as_uint(acc1b[r]) & 0xFFFFFC00u) | oB);
      float hi2 = fmaxf(kc, kd), lo2 = fminf(kc, kd);
      m2[4+r] = fmaxf(fmaxf(fminf(m1[4+r], hi2), lo2), m2[4+r]);
      m1[4+r] = fmaxf(m1[4+r], hi2);
    }
    orb -= 32;
  }

  __syncthreads();          // all waves past Ah loads; zh reusable as cand
  // 32 class semis per token; stride 36 floats (16B-aligned rows)
  #pragma unroll
  for (int mt = 0; mt < 2; ++mt)
    #pragma unroll
    for (int r = 0; r < 4; ++r) {
      const int tok = w * 32 + mt * 16 + quad * 4 + r;  // C/D row (verified)
      cand[tok * 36 + nn]      = m1[mt * 4 + r];
      cand[tok * 36 + 16 + nn] = m2[mt * 4 + r];
    }
  __syncthreads();

  // thread == token (tid<256): top-4 of 32 keys, then exact recheck
  if (tid < 256) {
    float bv[4] = {-3.4e38f, -3.4e38f, -3.4e38f, -3.4e38f};
    const float4* cp = (const float4*)(cand + tid * 36);
    #pragma unroll
    for (int i4 = 0; i4 < 8; ++i4) {
      float4 v = cp[i4];
      float av[4] = {v.x, v.y, v.z, v.w};
      #pragma unroll
      for (int e = 0; e < 4; ++e) {
        float a = av[e];
        #pragma unroll
        for (int j = 0; j < 4; ++j) {
          bool ins = a > bv[j];
          float t = bv[j]; bv[j] = ins ? a : bv[j]; a = ins ? t : a;
        }
      }
    }
    const int k0 = 1023 - (int)(__float_as_uint(bv[0]) & 1023u);
    const int k1 = 1023 - (int)(__float_as_uint(bv[1]) & 1023u);
    const int k2 = 1023 - (int)(__float_as_uint(bv[2]) & 1023u);
    const int k3 = 1023 - (int)(__float_as_uint(bv[3]) & 1023u);
    const float4* e0p = (const float4*)(emb + (size_t)k0 * CH);
    const float4* e1p = (const float4*)(emb + (size_t)k1 * CH);
    const float4* e2p = (const float4*)(emb + (size_t)k2 * CH);
    const float4* e3p = (const float4*)(emb + (size_t)k3 * CH);
    const float* zt = zbase + tid;
    float znorm = 0.f, d0 = 0.f, d1 = 0.f, d2 = 0.f, d3 = 0.f;
    #pragma unroll 4
    for (int c4 = 0; c4 < 16; ++c4) {
      float4 ev0 = e0p[c4];
      float4 ev1 = e1p[c4];
      float4 ev2 = e2p[c4];
      float4 ev3 = e3p[c4];
      float v0 = zt[(size_t)(4*c4+0) * DHWC];
      float v1 = zt[(size_t)(4*c4+1) * DHWC];
      float v2 = zt[(size_t)(4*c4+2) * DHWC];
      float v3 = zt[(size_t)(4*c4+3) * DHWC];
      znorm = fmaf(v0, v0, znorm); znorm = fmaf(v1, v1, znorm);
      znorm = fmaf(v2, v2, znorm); znorm = fmaf(v3, v3, znorm);
      d0 = fmaf(v0, ev0.x, d0); d0 = fmaf(v1, ev0.y, d0);
      d0 = fmaf(v2, ev0.z, d0); d0 = fmaf(v3, ev0.w, d0);
      d1 = fmaf(v0, ev1.x, d1); d1 = fmaf(v1, ev1.y, d1);
      d1 = fmaf(v2, ev1.z, d1); d1 = fmaf(v3, ev1.w, d1);
      d2 = fmaf(v0, ev2.x, d2); d2 = fmaf(v1, ev2.y, d2);
      d2 = fmaf(v2, ev2.z, d2); d2 = fmaf(v3, ev2.w, d2);
      d3 = fmaf(v0, ev3.x, d3); d3 = fmaf(v1, ev3.y, d3);
      d3 = fmaf(v2, ev3.z, d3); d3 = fmaf(v3, ev3.w, d3);
    }
    float dd0 = fmaf(-2.f, d0, znorm + ws->e_norm[k0]);
    float dd1 = fmaf(-2.f, d1, znorm + ws->e_norm[k1]);
    float dd2 = fmaf(-2.f, d2, znorm + ws->e_norm[k2]);
    float dd3 = fmaf(-2.f, d3, znorm + ws->e_norm[k3]);
    float dd = dd0; int kk = k0;
    if (dd1 < dd || (dd1 == dd && k1 < kk)) { dd = dd1; kk = k1; }
    if (dd2 < dd || (dd2 == dd && k2 < kk)) { dd = dd2; kk = k2; }
    if (dd3 < dd || (dd3 == dd && k3 < kk)) { dd = dd3; kk = k3; }
    ws->hd[h * NTOK + n0 + tid] = dd;
    ws->hk[h * NTOK + n0 + tid] = (unsigned short)kk;
  }
}

// ---- phase 3: combine halves + output + loss + counts (R0-verified) -----
// grid 256 x 1024; block = ONE (b,c) plane.
__global__ __launch_bounds__(1024, 4)
void vq_writer(const float* __restrict__ z, const float* __restrict__ emb,
               float* __restrict__ out, Ws* __restrict__ ws) {
  __shared__ float ecol[KCODES];     // column c of emb (4 KB)
  __shared__ int   hist[KCODES];     // LDS histogram (c==0 blocks only)
  __shared__ float sh[16];
  const int p   = blockIdx.x;        // plane: b*64 + c
  const int tid = threadIdx.x;
  const int b = p >> 6, c = p & 63;
  const bool docnt = (c == 0);
  ecol[tid] = emb[(size_t)tid * CH + c];
  if (docnt) hist[tid] = 0;
  __syncthreads();

  const size_t base = (size_t)p * DHWC;
  const float4* zp = (const float4*)(z + base);
  float4* op = (float4*)(out + base);
  const int nbase = b * 16384;
  const float*          hd0 = ws->hd + nbase;
  const float*          hd1 = ws->hd + NTOK + nbase;
  const unsigned short* hk0 = ws->hk + nbase;
  const unsigned short* hk1 = ws->hk + NTOK + nbase;
  float lp = 0.f;
  #pragma unroll
  for (int i = tid; i < 4096; i += 1024) {         // 4 iterations
    float4 v  = zp[i];
    float4 d0 = *(const float4*)(hd0 + 4 * i);
    float4 d1 = *(const float4*)(hd1 + 4 * i);
    ushort4 ka = *(const ushort4*)(hk0 + 4 * i);
    ushort4 kb = *(const ushort4*)(hk1 + 4 * i);
    int w0 = (d0.x < d1.x || (d0.x == d1.x && ka.x < kb.x)) ? ka.x : kb.x;
    int w1 = (d0.y < d1.y || (d0.y == d1.y && ka.y < kb.y)) ? ka.y : kb.y;
    int w2 = (d0.z < d1.z || (d0.z == d1.z && ka.z < kb.z)) ? ka.z : kb.z;
    int w3 = (d0.w < d1.w || (d0.w == d1.w && ka.w < kb.w)) ? ka.w : kb.w;
    float q0 = ecol[w0], q1 = ecol[w1], q2 = ecol[w2], q3 = ecol[w3];
    float e0 = q0 - v.x, e1 = q1 - v.y, e2 = q2 - v.z, e3 = q3 - v.w;
    float4 o; o.x = v.x + e0; o.y = v.y + e1; o.z = v.z + e2; o.w = v.w + e3;
    op[i] = o;
    lp = fmaf(e0, e0, lp); lp = fmaf(e1, e1, lp);
    lp = fmaf(e2, e2, lp); lp = fmaf(e3, e3, lp);
    if (docnt) {
      atomicAdd(&hist[w0], 1);
      atomicAdd(&hist[w1], 1);
      atomicAdd(&hist[w2], 1);
      atomicAdd(&hist[w3], 1);
    }
  }
  #pragma unroll
  for (int off = 32; off > 0; off >>= 1) lp += __shfl_down(lp, off);
  if ((tid & 63) == 0) sh[tid >> 6] = lp;
  __syncthreads();
  if (docnt) {
    int h2 = hist[tid];
    if (h2) atomicAdd(&ws->counts[tid], h2);
  }
  if (tid == 0) {
    float t = 0.f;
    #pragma unroll
    for (int i = 0; i < 16; ++i) t += sh[i];
    atomicAdd(&ws->loss_sum, (double)t);
  }
}

// ---- final: scalars (R0-verified) ---------------------------------------
__global__ void vq_final(Ws* __restrict__ ws, float* __restrict__ out_scalars) {
  const int tid = threadIdx.x;
  float p = (float)ws->counts[tid] * (1.0f / 65536.0f);
  float term = p * logf(p + 1e-10f);
  __shared__ float sh[1024];
  sh[tid] = term;
  __syncthreads();
  for (int off = 512; off > 0; off >>= 1) {
    if (tid < off) sh[tid] += sh[tid + off];
    __syncthreads();
  }
  if (tid == 0) {
    float perp = expf(-sh[0]);
    double m = ws->loss_sum / (double)OUT_ELEMS;
    float mf = (float)m;
    float loss = mf + 0.25f * mf;
    double sdot = 0.0;
    #pragma unroll
    for (int c = 0; c < CH; ++c) sdot += (double)ws->sum_z[c] * ws->sum_e[c];
    double md = ws->sum_z2 / (double)NTOK + ws->sum_e2 / (double)KCODES
              - 2.0 * sdot / ((double)NTOK * (double)KCODES);
    out_scalars[0] = loss;
    out_scalars[1] = perp;
    out_scalars[2] = (float)md;
  }
}

extern "C" void kernel_launch(void* const* d_in, const int* in_sizes, int n_in,
                              void* d_out, int out_size, void* d_ws, size_t ws_size,
                              hipStream_t stream) {
  const float* z   = (const float*)d_in[0];
  const float* emb = (const float*)d_in[1];
  float* out = (float*)d_out;
  Ws* ws = (Ws*)d_ws;

  hipMemsetAsync(d_ws, 0, offsetof(Ws, e_norm), stream);
  vq_eprep <<<16,   256,  0, stream>>>(emb, ws);
  vq_gemm  <<<512,  512,  0, stream>>>(z, emb, ws);
  vq_writer<<<256,  1024, 0, stream>>>(z, emb, out, ws);
  vq_final <<<1,    1024, 0, stream>>>(ws, out + OUT_ELEMS);
}

// Round 6
// 116.970 us; speedup vs baseline: 1.9434x; 1.1280x over previous
//
#include <hip/hip_runtime.h>
#include <hip/hip_bf16.h>
#include <math.h>
#include <stddef.h>

// Problem shape: z [4,64,16,32,32] fp32, embedding [1024,64] fp32
#define CH     64
#define DHWC   16384
#define NTOK   65536
#define KCODES 1024
#define OUT_ELEMS 4194304

typedef _Float16 f16;
typedef f16  f16x8  __attribute__((ext_vector_type(8)));
typedef float fltx4 __attribute__((ext_vector_type(4)));

struct Ws {
  // ---- zeroed header (memset range = offsetof(Ws, e_norm)) ----
  double sum_z2, sum_e2, loss_sum, pad;
  float  sum_z[CH];               // f32 atomics (now from writer blocks)
  double sum_e[CH];
  int    counts[KCODES];
  // ---- filled by eprep ----
  float  e_norm[KCODES];
  float  accI[KCODES + 48];       // -e_norm/2 (+pad)
  // codebook pre-swizzled into MFMA B-fragment order (verified layout)
  alignas(16) f16 e_frag[(64 + 2) * 2 * 64 * 8];
  // ---- per-half exact winners (gemm -> writer) ----
  float          hd[2 * NTOK];
  unsigned short hk[2 * NTOK];
};

// ---- eprep: e_norm (exact chain) + e-sums + fragments (verified) --------
__global__ void vq_eprep(const float* __restrict__ emb, Ws* __restrict__ ws) {
  __shared__ float tile[64][68];
  __shared__ float red[256];
  const int tid = threadIdx.x;
  const int r = tid >> 2;                 // code row within block (0..63)
  const int q = tid & 3;                  // quarter of the 64-channel row
  const int k = blockIdx.x * 64 + r;
  const float4* src = (const float4*)(emb + (size_t)k * CH + q * 16);
  float4 a = src[0], b = src[1], c = src[2], d = src[3];
  float4* dst = (float4*)(&tile[r][q * 16]);
  dst[0] = a; dst[1] = b; dst[2] = c; dst[3] = d;
  float s2 = 0.f;
  s2 = fmaf(a.x,a.x,s2); s2 = fmaf(a.y,a.y,s2); s2 = fmaf(a.z,a.z,s2); s2 = fmaf(a.w,a.w,s2);
  s2 = fmaf(b.x,b.x,s2); s2 = fmaf(b.y,b.y,s2); s2 = fmaf(b.z,b.z,s2); s2 = fmaf(b.w,b.w,s2);
  s2 = fmaf(c.x,c.x,s2); s2 = fmaf(c.y,c.y,s2); s2 = fmaf(c.z,c.z,s2); s2 = fmaf(c.w,c.w,s2);
  s2 = fmaf(d.x,d.x,s2); s2 = fmaf(d.y,d.y,s2); s2 = fmaf(d.z,d.z,s2); s2 = fmaf(d.w,d.w,s2);
  // verified-exact row norm (absmax 0.0)
  float t1 = s2 + __shfl_xor(s2, 1);
  float t2 = t1 + __shfl_xor(t1, 2);
  if (q == 0) { ws->e_norm[k] = t2; ws->accI[k] = -0.5f * t2; }
  // pre-swizzled B-fragment write (verified)
  {
    float vals[16] = {a.x,a.y,a.z,a.w, b.x,b.y,b.z,b.w,
                      c.x,c.y,c.z,c.w, d.x,d.y,d.z,d.w};
    const int ct  = blockIdx.x * 4 + (r >> 4);
    const int nn  = r & 15;
    const int b01 = q >> 1;
    const int qd0 = (q & 1) * 2;
    f16 h8a[8], h8b[8];
    #pragma unroll
    for (int u = 0; u < 8; ++u) { h8a[u] = (f16)vals[u]; h8b[u] = (f16)vals[8 + u]; }
    f16x8* fr = (f16x8*)ws->e_frag;
    fr[(ct * 2 + b01) * 64 + (qd0 + 0) * 16 + nn] = *(f16x8*)h8a;
    fr[(ct * 2 + b01) * 64 + (qd0 + 1) * 16 + nn] = *(f16x8*)h8b;
  }
  red[tid] = s2;
  __syncthreads();
  for (int off = 128; off > 0; off >>= 1) {
    if (tid < off) red[tid] += red[tid + off];
    __syncthreads();
  }
  if (tid == 0) atomicAdd(&ws->sum_e2, (double)red[0]);
  if (tid < CH) {
    float cs = 0.f;
    #pragma unroll 8
    for (int rr = 0; rr < 64; ++rr) cs += tile[rr][tid];
    atomicAdd(&ws->sum_e[tid], (double)cs);
  }
}

// ---- phase 1+2: B-in-LDS MFMA + in-wave tournament + exact recheck ------
// R6: grid 512 = 256 tg x 2 halves; 512 threads; 68.6 KB LDS -> 2 blocks/CU
// (16 waves/CU, 2x R5). A-fragments loaded directly from global z (no zh
// tile, no staging barrier); per-class top-2 (verified packed keys) merged
// to exact per-half top-2 by a 4-step shfl_xor tournament (no cand array,
// no LDS bank conflicts). Recheck: 2 threads/token, 1 candidate each.
__global__ __launch_bounds__(512, 4)
void vq_gemm(const float* __restrict__ z, const float* __restrict__ emb,
             Ws* __restrict__ ws) {
  // LDS 68608 B: [0,65536) ef; [65536,67584) accl; [67584,68608) candm
  __shared__ char smem[68608];
  f16x8*    efr   = (f16x8*)smem;
  float*    accl  = (float*)(smem + 65536);
  unsigned* candm = (unsigned*)(smem + 67584);

  const int tid = threadIdx.x;
  const int h   = blockIdx.x & 1;          // K-half
  const int tg  = blockIdx.x >> 1;         // token group (256 tokens)
  const int n0  = tg * 256;
  const int b   = n0 >> 14;
  const int s0  = n0 & 16383;
  const float* zbase = z + (size_t)b * (CH * DHWC) + s0;

  // stage B-half + accI-half into LDS (coalesced 16B/lane, 8 rounds)
  {
    const f16x8* gsrc = ((const f16x8*)ws->e_frag) + h * 4096;
    #pragma unroll
    for (int r = 0; r < 8; ++r)
      efr[r * 512 + tid] = gsrc[r * 512 + tid];
    accl[tid] = ws->accI[h * 512 + tid];
  }

  const int lane = tid & 63;
  const int w    = tid >> 6;           // wave: tokens [w*32, w*32+32)
  const int nn   = lane & 15;          // MFMA column (code class)
  const int quad = lane >> 4;

  // A fragments DIRECT from global (same f16 RNE cvt as the staged path):
  // Ah[mt][ks][j] = (f16) z[ch=ks*32+quad*8+j][tok=w*32+mt*16+nn]
  f16x8 Ah[2][2];
  #pragma unroll
  for (int mt = 0; mt < 2; ++mt) {
    const int row = w * 32 + mt * 16 + nn;
    #pragma unroll
    for (int ks = 0; ks < 2; ++ks) {
      f16 tmp[8];
      #pragma unroll
      for (int j = 0; j < 8; ++j)
        tmp[j] = (f16)zbase[(size_t)(ks * 32 + quad * 8 + j) * DHWC + row];
      Ah[mt][ks] = *(f16x8*)tmp;
    }
  }
  __syncthreads();                     // ef/accl staged

  // packed-key top-2 per (token-slot, class):
  // key = (score bits & ~1023) | (1023 - k): distinct keys, max = best,
  // k decodable from low 10 bits; exact distances restored by recheck.
  float m1[8], m2[8];
  #pragma unroll
  for (int u = 0; u < 8; ++u) { m1[u] = -3.4e38f; m2[u] = -3.4e38f; }

  const f16x8* Bp = efr + lane;
  unsigned orb = (unsigned)(1023 - h * 512 - nn);
  #pragma unroll 4
  for (int itp = 0; itp < 16; ++itp) {     // ct-pair per iteration
    const int c0 = itp * 2;
    f16x8 B0a = Bp[(c0 * 2 + 0) * 64];
    f16x8 B1a = Bp[(c0 * 2 + 1) * 64];
    f16x8 B0b = Bp[(c0 * 2 + 2) * 64];
    f16x8 B1b = Bp[(c0 * 2 + 3) * 64];
    const float aia = accl[c0 * 16 + nn];
    const float aib = accl[c0 * 16 + 16 + nn];
    fltx4 acc0a = {aia, aia, aia, aia};
    acc0a = __builtin_amdgcn_mfma_f32_16x16x32_f16(Ah[0][0], B0a, acc0a, 0, 0, 0);
    acc0a = __builtin_amdgcn_mfma_f32_16x16x32_f16(Ah[0][1], B1a, acc0a, 0, 0, 0);
    fltx4 acc1a = {aia, aia, aia, aia};
    acc1a = __builtin_amdgcn_mfma_f32_16x16x32_f16(Ah[1][0], B0a, acc1a, 0, 0, 0);
    acc1a = __builtin_amdgcn_mfma_f32_16x16x32_f16(Ah[1][1], B1a, acc1a, 0, 0, 0);
    fltx4 acc0b = {aib, aib, aib, aib};
    acc0b = __builtin_amdgcn_mfma_f32_16x16x32_f16(Ah[0][0], B0b, acc0b, 0, 0, 0);
    acc0b = __builtin_amdgcn_mfma_f32_16x16x32_f16(Ah[0][1], B1b, acc0b, 0, 0, 0);
    fltx4 acc1b = {aib, aib, aib, aib};
    acc1b = __builtin_amdgcn_mfma_f32_16x16x32_f16(Ah[1][0], B0b, acc1b, 0, 0, 0);
    acc1b = __builtin_amdgcn_mfma_f32_16x16x32_f16(Ah[1][1], B1b, acc1b, 0, 0, 0);
    const unsigned oA = orb, oB = orb - 16;
    #pragma unroll
    for (int r = 0; r < 4; ++r) {
      float ka = __uint_as_float((__float_as_uint(acc0a[r]) & 0xFFFFFC00u) | oA);
      float kb = __uint_as_float((__float_as_uint(acc0b[r]) & 0xFFFFFC00u) | oB);
      float hi = fmaxf(ka, kb), lo = fminf(ka, kb);
      m2[r] = fmaxf(fmaxf(fminf(m1[r], hi), lo), m2[r]);
      m1[r] = fmaxf(m1[r], hi);
      float kc = __uint_as_float((__float_as_uint(acc1a[r]) & 0xFFFFFC00u) | oA);
      float kd = __uint_as_float((__float_as_uint(acc1b[r]) & 0xFFFFFC00u) | oB);
      float hi2 = fmaxf(kc, kd), lo2 = fminf(kc, kd);
      m2[4+r] = fmaxf(fmaxf(fminf(m1[4+r], hi2), lo2), m2[4+r]);
      m1[4+r] = fmaxf(m1[4+r], hi2);
    }
    orb -= 32;
  }

  // in-wave tournament across the 16 nn-lanes: exact top-2 of the half.
  // merge of sorted pairs: m1'=max(m1,o1); m2'=max(min(m1,o1),max(m2,o2)).
  #pragma unroll
  for (int s = 1; s <= 8; s <<= 1) {
    #pragma unroll
    for (int u = 0; u < 8; ++u) {
      float o1 = __shfl_xor(m1[u], s);
      float o2 = __shfl_xor(m2[u], s);
      float lo = fminf(m1[u], o1);
      m1[u] = fmaxf(m1[u], o1);
      m2[u] = fmaxf(lo, fmaxf(m2[u], o2));
    }
  }
  if (nn == 0) {
    #pragma unroll
    for (int mt = 0; mt < 2; ++mt)
      #pragma unroll
      for (int r = 0; r < 4; ++r) {
        const int u = mt * 4 + r;
        const int tok = w * 32 + mt * 16 + quad * 4 + r;  // C/D row (verified)
        unsigned kA = 1023u - (__float_as_uint(m1[u]) & 1023u);
        unsigned kB = 1023u - (__float_as_uint(m2[u]) & 1023u);
        candm[tok] = kA | (kB << 16);
      }
  }
  __syncthreads();

  // exact recheck (verified chain): 2 threads/token, 1 candidate each
  {
    const int tok = tid >> 1, j = tid & 1;
    const unsigned cd = candm[tok];
    const int kc = (int)((j ? (cd >> 16) : cd) & 0xffffu);
    const float4* ep = (const float4*)(emb + (size_t)kc * CH);
    const float* zt = zbase + tok;
    float znorm = 0.f, dpr = 0.f;
    #pragma unroll 4
    for (int c4 = 0; c4 < 16; ++c4) {
      float4 ev = ep[c4];
      float v0 = zt[(size_t)(4*c4+0) * DHWC];
      float v1 = zt[(size_t)(4*c4+1) * DHWC];
      float v2 = zt[(size_t)(4*c4+2) * DHWC];
      float v3 = zt[(size_t)(4*c4+3) * DHWC];
      znorm = fmaf(v0, v0, znorm); znorm = fmaf(v1, v1, znorm);
      znorm = fmaf(v2, v2, znorm); znorm = fmaf(v3, v3, znorm);
      dpr = fmaf(v0, ev.x, dpr); dpr = fmaf(v1, ev.y, dpr);
      dpr = fmaf(v2, ev.z, dpr); dpr = fmaf(v3, ev.w, dpr);
    }
    float dd = fmaf(-2.f, dpr, znorm + ws->e_norm[kc]);
    int   kk = kc;
    float od = __shfl_xor(dd, 1); int ok = __shfl_xor(kk, 1);
    if (od < dd || (od == dd && ok < kk)) { dd = od; kk = ok; }
    if (j == 0) {
      ws->hd[h * NTOK + n0 + tok] = dd;
      ws->hk[h * NTOK + n0 + tok] = (unsigned short)kk;
    }
  }
}

// ---- phase 3: combine halves + output + loss + counts + z-sums ----------
// grid 256 x 1024; block = ONE (b,c) plane (R0-verified core).
__global__ __launch_bounds__(1024, 4)
void vq_writer(const float* __restrict__ z, const float* __restrict__ emb,
               float* __restrict__ out, Ws* __restrict__ ws) {
  __shared__ float ecol[KCODES];     // column c of emb (4 KB)
  __shared__ int   hist[KCODES];     // LDS histogram (c==0 blocks only)
  __shared__ float sh[48];
  const int p   = blockIdx.x;        // plane: b*64 + c
  const int tid = threadIdx.x;
  const int b = p >> 6, c = p & 63;
  const bool docnt = (c == 0);
  ecol[tid] = emb[(size_t)tid * CH + c];
  if (docnt) hist[tid] = 0;
  __syncthreads();

  const size_t base = (size_t)p * DHWC;
  const float4* zp = (const float4*)(z + base);
  float4* op = (float4*)(out + base);
  const int nbase = b * 16384;
  const float*          hd0 = ws->hd + nbase;
  const float*          hd1 = ws->hd + NTOK + nbase;
  const unsigned short* hk0 = ws->hk + nbase;
  const unsigned short* hk1 = ws->hk + NTOK + nbase;
  float lp = 0.f, ss = 0.f, ss2 = 0.f;
  #pragma unroll
  for (int i = tid; i < 4096; i += 1024) {         // 4 iterations
    float4 v  = zp[i];
    float4 d0 = *(const float4*)(hd0 + 4 * i);
    float4 d1 = *(const float4*)(hd1 + 4 * i);
    ushort4 ka = *(const ushort4*)(hk0 + 4 * i);
    ushort4 kb = *(const ushort4*)(hk1 + 4 * i);
    int w0 = (d0.x < d1.x || (d0.x == d1.x && ka.x < kb.x)) ? ka.x : kb.x;
    int w1 = (d0.y < d1.y || (d0.y == d1.y && ka.y < kb.y)) ? ka.y : kb.y;
    int w2 = (d0.z < d1.z || (d0.z == d1.z && ka.z < kb.z)) ? ka.z : kb.z;
    int w3 = (d0.w < d1.w || (d0.w == d1.w && ka.w < kb.w)) ? ka.w : kb.w;
    float q0 = ecol[w0], q1 = ecol[w1], q2 = ecol[w2], q3 = ecol[w3];
    float e0 = q0 - v.x, e1 = q1 - v.y, e2 = q2 - v.z, e3 = q3 - v.w;
    float4 o; o.x = v.x + e0; o.y = v.y + e1; o.z = v.z + e2; o.w = v.w + e3;
    op[i] = o;
    lp = fmaf(e0, e0, lp); lp = fmaf(e1, e1, lp);
    lp = fmaf(e2, e2, lp); lp = fmaf(e3, e3, lp);
    ss += v.x + v.y + v.z + v.w;
    ss2 = fmaf(v.x, v.x, ss2); ss2 = fmaf(v.y, v.y, ss2);
    ss2 = fmaf(v.z, v.z, ss2); ss2 = fmaf(v.w, v.w, ss2);
    if (docnt) {
      atomicAdd(&hist[w0], 1);
      atomicAdd(&hist[w1], 1);
      atomicAdd(&hist[w2], 1);
      atomicAdd(&hist[w3], 1);
    }
  }
  #pragma unroll
  for (int off = 32; off > 0; off >>= 1) {
    lp  += __shfl_down(lp, off);
    ss  += __shfl_down(ss, off);
    ss2 += __shfl_down(ss2, off);
  }
  if ((tid & 63) == 0) {
    sh[tid >> 6] = lp; sh[16 + (tid >> 6)] = ss; sh[32 + (tid >> 6)] = ss2;
  }
  __syncthreads();
  if (docnt) {
    int h2 = hist[tid];
    if (h2) atomicAdd(&ws->counts[tid], h2);
  }
  if (tid == 0) {
    float t = 0.f, tz = 0.f, tz2 = 0.f;
    #pragma unroll
    for (int i = 0; i < 16; ++i) { t += sh[i]; tz += sh[16+i]; tz2 += sh[32+i]; }
    atomicAdd(&ws->loss_sum, (double)t);
    atomicAdd(&ws->sum_z[c], tz);
    atomicAdd(&ws->sum_z2, (double)tz2);
  }
}

// ---- final: scalars (R0-verified) ---------------------------------------
__global__ void vq_final(Ws* __restrict__ ws, float* __restrict__ out_scalars) {
  const int tid = threadIdx.x;
  float p = (float)ws->counts[tid] * (1.0f / 65536.0f);
  float term = p * logf(p + 1e-10f);
  __shared__ float sh[1024];
  sh[tid] = term;
  __syncthreads();
  for (int off = 512; off > 0; off >>= 1) {
    if (tid < off) sh[tid] += sh[tid + off];
    __syncthreads();
  }
  if (tid == 0) {
    float perp = expf(-sh[0]);
    double m = ws->loss_sum / (double)OUT_ELEMS;
    float mf = (float)m;
    float loss = mf + 0.25f * mf;
    double sdot = 0.0;
    #pragma unroll
    for (int c = 0; c < CH; ++c) sdot += (double)ws->sum_z[c] * ws->sum_e[c];
    double md = ws->sum_z2 / (double)NTOK + ws->sum_e2 / (double)KCODES
              - 2.0 * sdot / ((double)NTOK * (double)KCODES);
    out_scalars[0] = loss;
    out_scalars[1] = perp;
    out_scalars[2] = (float)md;
  }
}

extern "C" void kernel_launch(void* const* d_in, const int* in_sizes, int n_in,
                              void* d_out, int out_size, void* d_ws, size_t ws_size,
                              hipStream_t stream) {
  const float* z   = (const float*)d_in[0];
  const float* emb = (const float*)d_in[1];
  float* out = (float*)d_out;
  Ws* ws = (Ws*)d_ws;

  hipMemsetAsync(d_ws, 0, offsetof(Ws, e_norm), stream);
  vq_eprep <<<16,   256,  0, stream>>>(emb, ws);
  vq_gemm  <<<512,  512,  0, stream>>>(z, emb, ws);
  vq_writer<<<256,  1024, 0, stream>>>(z, emb, out, ws);
  vq_final <<<1,    1024, 0, stream>>>(ws, out + OUT_ELEMS);
}